// Round 4
// baseline (289.712 us; speedup 1.0000x reference)
//
#include <hip/hip_runtime.h>
#include <hip/hip_bf16.h>

#define N_    2048
#define FIN   256
#define FOUT  128
#define ALPHA 0.01f

typedef short bf16x8 __attribute__((ext_vector_type(8)));
typedef float f32x4  __attribute__((ext_vector_type(4)));

static __device__ __forceinline__ unsigned short f2bf(float x) {
    __hip_bfloat16 h = __float2bfloat16(x);
    return *reinterpret_cast<unsigned short*>(&h);
}
static __device__ __forceinline__ float bf2f(unsigned short u) {
    return __uint_as_float(((unsigned)u) << 16);
}

// ---------------------------------------------------------------------------
// W split: W[256][128] fp32 -> WThi/WTlo[128][256] bf16 (transposed, hi+lo)
__global__ __launch_bounds__(256) void k_wsplit(
    const float* __restrict__ W, unsigned short* __restrict__ WThi,
    unsigned short* __restrict__ WTlo)
{
    int idx = blockIdx.x * 256 + threadIdx.x;   // 32768
    int k = idx >> 7, n = idx & 127;
    float w = W[k * 128 + n];
    unsigned short hi = f2bf(w);
    unsigned short lo = f2bf(w - bf2f(hi));
    WThi[n * 256 + k] = hi;
    WTlo[n * 256 + k] = lo;
}

// ---------------------------------------------------------------------------
// adj pack: one block per row; byte (S,lg,w) = bits of adj[row][w*512+S*32+lg*8 ..+7]
// layout: mask[row*256 + w*64 + lg*16 + S]
__global__ __launch_bounds__(256) void k_pack(
    const int* __restrict__ adj, unsigned int* __restrict__ mask)
{
    __shared__ unsigned char mb[256];
    int row = blockIdx.x;                       // 16384 = b*2048 + i
    int t = threadIdx.x;
    const int4* a4 = reinterpret_cast<const int4*>(adj + (size_t)row * N_) + 2 * t;
    int4 x = a4[0], y = a4[1];
    unsigned byte =
        (unsigned)(x.x > 0) | ((unsigned)(x.y > 0) << 1) |
        ((unsigned)(x.z > 0) << 2) | ((unsigned)(x.w > 0) << 3) |
        ((unsigned)(y.x > 0) << 4) | ((unsigned)(y.y > 0) << 5) |
        ((unsigned)(y.z > 0) << 6) | ((unsigned)(y.w > 0) << 7);
    int w = t >> 6, cig = t & 63;
    int S = cig >> 2, lg = cig & 3;
    mb[w * 64 + lg * 16 + S] = (unsigned char)byte;
    __syncthreads();
    if (t < 16)
        reinterpret_cast<uint4*>(mask)[row * 16 + t] =
            reinterpret_cast<const uint4*>(mb)[t];
}

// ---------------------------------------------------------------------------
// h = inp @ W via 3-term split-bf16 MFMA (fp32-grade accuracy).
// Block: 64 rows x 128 cols, 4 waves (16 rows each). Emits hT bf16 + s1/s2 fp32.
__global__ __launch_bounds__(256) void k_lin(
    const float* __restrict__ inp,
    const unsigned short* __restrict__ WThi, const unsigned short* __restrict__ WTlo,
    const float* __restrict__ av, unsigned short* __restrict__ hT,
    float* __restrict__ s1, float* __restrict__ s2)
{
    __shared__ unsigned short Ahi[64 * 256];   // 32 KB, XOR-swizzled rows
    __shared__ unsigned short Alo[64 * 256];   // 32 KB

    int g = blockIdx.x;            // 256 blocks
    int b = g & 7;
    int i0 = (g >> 3) << 6;        // 64-row tile
    int t = threadIdx.x;

    // stage: thread t -> row t>>2, k-segment (t&3)*64; 8 groups of 8 floats
    {
        int row = t >> 2;
        const float* src = inp + ((size_t)(b * N_ + i0 + row)) * FIN + (t & 3) * 64;
#pragma unroll
        for (int gseg = 0; gseg < 8; ++gseg) {
            float4 f0 = *reinterpret_cast<const float4*>(src + gseg * 8);
            float4 f1 = *reinterpret_cast<const float4*>(src + gseg * 8 + 4);
            float f[8] = {f0.x, f0.y, f0.z, f0.w, f1.x, f1.y, f1.z, f1.w};
            bf16x8 hi8, lo8;
#pragma unroll
            for (int e = 0; e < 8; ++e) {
                unsigned short h = f2bf(f[e]);
                hi8[e] = (short)h;
                lo8[e] = (short)f2bf(f[e] - bf2f(h));
            }
            int k = (t & 3) * 64 + gseg * 8;
            int off = (row * 512 + k * 2) ^ ((row & 7) << 4);
            *reinterpret_cast<bf16x8*>(reinterpret_cast<char*>(Ahi) + off) = hi8;
            *reinterpret_cast<bf16x8*>(reinterpret_cast<char*>(Alo) + off) = lo8;
        }
    }
    __syncthreads();

    int w = t >> 6, l = t & 63;
    int ln = l & 15, lg = l >> 4;
    const bf16x8* Whi8 = reinterpret_cast<const bf16x8*>(WThi);
    const bf16x8* Wlo8 = reinterpret_cast<const bf16x8*>(WTlo);

    f32x4 acc[8];
#pragma unroll
    for (int nb = 0; nb < 8; ++nb) acc[nb] = (f32x4){0.f, 0.f, 0.f, 0.f};

#pragma unroll
    for (int ks = 0; ks < 8; ++ks) {
        int arow = w * 16 + ln;
        int aoff = (arow * 512 + ks * 64 + lg * 16) ^ ((arow & 7) << 4);
        bf16x8 ahi = *reinterpret_cast<const bf16x8*>(reinterpret_cast<const char*>(Ahi) + aoff);
        bf16x8 alo = *reinterpret_cast<const bf16x8*>(reinterpret_cast<const char*>(Alo) + aoff);
#pragma unroll
        for (int nb = 0; nb < 8; ++nb) {
            int n = nb * 16 + ln;
            bf16x8 whi = Whi8[n * 32 + ks * 4 + lg];
            bf16x8 wlo = Wlo8[n * 32 + ks * 4 + lg];
            acc[nb] = __builtin_amdgcn_mfma_f32_16x16x32_bf16(ahi, whi, acc[nb], 0, 0, 0);
            acc[nb] = __builtin_amdgcn_mfma_f32_16x16x32_bf16(alo, whi, acc[nb], 0, 0, 0);
            acc[nb] = __builtin_amdgcn_mfma_f32_16x16x32_bf16(ahi, wlo, acc[nb], 0, 0, 0);
        }
    }

    // s1/s2: C/D layout col=ln (n = nb*16+ln), row = lg*4+j
    float p1[4] = {0.f, 0.f, 0.f, 0.f}, p2[4] = {0.f, 0.f, 0.f, 0.f};
#pragma unroll
    for (int nb = 0; nb < 8; ++nb) {
        float a1 = av[nb * 16 + ln];
        float a2 = av[FOUT + nb * 16 + ln];
#pragma unroll
        for (int j = 0; j < 4; ++j) {
            p1[j] = fmaf(acc[nb][j], a1, p1[j]);
            p2[j] = fmaf(acc[nb][j], a2, p2[j]);
        }
    }
#pragma unroll
    for (int off = 1; off < 16; off <<= 1)
#pragma unroll
        for (int j = 0; j < 4; ++j) {
            p1[j] += __shfl_xor(p1[j], off);
            p2[j] += __shfl_xor(p2[j], off);
        }
    if (ln == 0) {
#pragma unroll
        for (int j = 0; j < 4; ++j) {
            int row = i0 + w * 16 + lg * 4 + j;
            s1[b * N_ + row] = p1[j];
            s2[b * N_ + row] = p2[j];
        }
    }

    // hT transpose through LDS (reuse Ahi): T[128 cols][68]
    __syncthreads();
    unsigned short* T = Ahi;
#pragma unroll
    for (int nb = 0; nb < 8; ++nb)
#pragma unroll
        for (int j = 0; j < 4; ++j)
            T[(nb * 16 + ln) * 68 + w * 16 + lg * 4 + j] = f2bf(acc[nb][j]);
    __syncthreads();
    {
        int f = t & 127, rh = t >> 7;
        unsigned short tmp[32];
#pragma unroll
        for (int c = 0; c < 32; ++c) tmp[c] = T[f * 68 + rh * 32 + c];
        int4* dst = reinterpret_cast<int4*>(&hT[((size_t)(b * FOUT + f)) * N_ + i0 + rh * 32]);
#pragma unroll
        for (int c = 0; c < 4; ++c) dst[c] = reinterpret_cast<const int4*>(tmp)[c];
    }
}

// ---------------------------------------------------------------------------
__global__ __launch_bounds__(256) void k_s2max(const float* __restrict__ s2,
                                               float* __restrict__ s2max)
{
    __shared__ float red[4];
    int b = blockIdx.x, t = threadIdx.x;
    const float4* p = reinterpret_cast<const float4*>(s2 + b * N_);
    float4 v0 = p[t], v1 = p[t + 256];
    float m = fmaxf(fmaxf(fmaxf(v0.x, v0.y), fmaxf(v0.z, v0.w)),
                    fmaxf(fmaxf(v1.x, v1.y), fmaxf(v1.z, v1.w)));
#pragma unroll
    for (int off = 1; off < 64; off <<= 1) m = fmaxf(m, __shfl_xor(m, off));
    if ((t & 63) == 0) red[t >> 6] = m;
    __syncthreads();
    if (t == 0) s2max[b] = fmaxf(fmaxf(red[0], red[1]), fmaxf(red[2], red[3]));
}

// ---------------------------------------------------------------------------
// Fused attention: mask bits (one uint4/lane for all 16 steps) + LDS s2 +
// L2-resident hT. Fixed softmax bound (no online rescale). Full unroll.
__global__ __launch_bounds__(256) void k_attn(
    const unsigned int* __restrict__ mask, const unsigned short* __restrict__ hT,
    const float* __restrict__ s1g, const float* __restrict__ s2g,
    const float* __restrict__ s2maxg, float* __restrict__ out)
{
    __shared__ float s2_lds[N_];         // 8 KB
    __shared__ float accb[4][16][128];   // 32 KB (epilogue only)
    __shared__ float l_s[4][16];

    int g = blockIdx.x;                  // 1024
    int b = g & 7;                       // XCD-affine
    int i0 = (g >> 3) << 4;              // 16 rows
    int t = threadIdx.x;
    int w = t >> 6, l = t & 63;
    int r = l & 15, lg = l >> 4;
    int jc = w * 512;

    {
        const float4* s2g4 = reinterpret_cast<const float4*>(s2g + b * N_);
        reinterpret_cast<float4*>(s2_lds)[t] = s2g4[t];
        reinterpret_cast<float4*>(s2_lds)[t + 256] = s2g4[t + 256];
    }

    const float s1r = s1g[b * N_ + i0 + r];
    float eb = s1r + s2maxg[b];
    const float m_row = fmaxf(eb, ALPHA * eb);

    // one uint4 = this lane's mask bytes for all 16 steps
    uint4 m4 = *reinterpret_cast<const uint4*>(
        reinterpret_cast<const char*>(mask) +
        ((size_t)(b * N_ + i0 + r)) * 256 + w * 64 + lg * 16);
    unsigned mw[4] = {m4.x, m4.y, m4.z, m4.w};

    const bf16x8* hvp = reinterpret_cast<const bf16x8*>(hT)
        + ((((size_t)(b * FOUT + r)) * N_ + jc + lg * 8) >> 3);

    __syncthreads();   // s2_lds ready

    float l_run = 0.0f;
    f32x4 acc[8];
#pragma unroll
    for (int q = 0; q < 8; ++q) acc[q] = (f32x4){0.f, 0.f, 0.f, 0.f};

    bf16x8 h0[8], h1[8];
#pragma unroll
    for (int q = 0; q < 8; ++q) h0[q] = hvp[q * 4096];

#pragma unroll
    for (int S = 0; S < 16; ++S) {
        auto& cur = (S & 1) ? h1 : h0;
        auto& nxt = (S & 1) ? h0 : h1;
        if (S < 15) {
#pragma unroll
            for (int q = 0; q < 8; ++q) nxt[q] = hvp[q * 4096 + (S + 1) * 4];
        }
        unsigned byte = (mw[S >> 2] >> ((S & 3) * 8)) & 0xffu;
        const float* s2b = &s2_lds[jc + S * 32 + lg * 8];
        float4 ca = *reinterpret_cast<const float4*>(s2b);
        float4 cb = *reinterpret_cast<const float4*>(s2b + 4);
        float sv[8] = {ca.x, ca.y, ca.z, ca.w, cb.x, cb.y, cb.z, cb.w};

        bf16x8 af;
        float ps = 0.f;
#pragma unroll
        for (int e = 0; e < 8; ++e) {
            float v = s1r + sv[e];
            v = fmaxf(v, ALPHA * v);
            float p = (byte & (1u << e)) ? __expf(v - m_row) : 0.f;
            ps += p;
            af[e] = (short)f2bf(p);
        }
        l_run += ps;
#pragma unroll
        for (int q = 0; q < 8; ++q)
            acc[q] = __builtin_amdgcn_mfma_f32_16x16x32_bf16(af, cur[q], acc[q], 0, 0, 0);
    }

    l_run += __shfl_xor(l_run, 16);
    l_run += __shfl_xor(l_run, 32);
    if (l < 16) l_s[w][l] = l_run;

#pragma unroll
    for (int q = 0; q < 8; ++q)
#pragma unroll
        for (int rr = 0; rr < 4; ++rr)
            accb[w][lg * 4 + rr][q * 16 + r] = acc[q][rr];
    __syncthreads();

    int f = t & 127, rh = t >> 7;
#pragma unroll
    for (int rr = 0; rr < 8; ++rr) {
        int row = rh * 8 + rr;
        float L = l_s[0][row] + l_s[1][row] + l_s[2][row] + l_s[3][row];
        float v = accb[0][row][f] + accb[1][row][f] + accb[2][row][f] + accb[3][row][f];
        out[((size_t)(b * N_ + i0 + row)) * FOUT + f] = fmaxf(v / L, 0.f);
    }
}

extern "C" void kernel_launch(void* const* d_in, const int* in_sizes, int n_in,
                              void* d_out, int out_size, void* d_ws, size_t ws_size,
                              hipStream_t stream) {
    (void)in_sizes; (void)n_in; (void)out_size; (void)ws_size;
    const float* inp = (const float*)d_in[0];
    const int*   adj = (const int*)d_in[1];
    const float* W   = (const float*)d_in[2];
    const float* a   = (const float*)d_in[3];
    float* out = (float*)d_out;

    char* ws = (char*)d_ws;
    unsigned short* hT   = (unsigned short*)ws;                         // 4 MB
    unsigned int*   mask = (unsigned int*)(ws + (4u << 20));            // 4 MB
    float* s1    = (float*)(ws + (8u << 20));                           // 64 KB
    float* s2    = s1 + 8 * N_;                                         // 64 KB
    unsigned short* WThi = (unsigned short*)(s2 + 8 * N_);              // 64 KB
    unsigned short* WTlo = WThi + FIN * FOUT;                           // 64 KB
    float* s2max = (float*)(WTlo + FIN * FOUT);                         // 32 B

    k_wsplit<<<128, 256, 0, stream>>>(W, WThi, WTlo);
    k_pack<<<8 * N_, 256, 0, stream>>>(adj, mask);
    k_lin<<<256, 256, 0, stream>>>(inp, WThi, WTlo, a, hT, s1, s2);
    k_s2max<<<8, 256, 0, stream>>>(s2, s2max);
    k_attn<<<1024, 256, 0, stream>>>(mask, hT, s1, s2, s2max, out);
}

// Round 6
// 253.239 us; speedup vs baseline: 1.1440x; 1.1440x over previous
//
#include <hip/hip_runtime.h>
#include <hip/hip_bf16.h>

#define N_    2048
#define FIN   256
#define FOUT  128
#define ALPHA 0.01f

typedef short bf16x8 __attribute__((ext_vector_type(8)));
typedef float f32x4  __attribute__((ext_vector_type(4)));

static __device__ __forceinline__ unsigned short f2bf(float x) {
    __hip_bfloat16 h = __float2bfloat16(x);
    return *reinterpret_cast<unsigned short*>(&h);
}
static __device__ __forceinline__ float bf2f(unsigned short u) {
    return __uint_as_float(((unsigned)u) << 16);
}

// ---------------------------------------------------------------------------
// W split -> FRAGMENT-MAJOR bf16 hi/lo: frag (nb,ks,lg) holds W[k=ks*32+lg*8+e][n=nb*16+ln],
// flat [(((nb*8+ks)*4+lg)*16+ln)*8+e]  => each MFMA B-frag load = 1024 contiguous bytes.
__global__ __launch_bounds__(256) void k_wsplit(
    const float* __restrict__ W, unsigned short* __restrict__ WFhi,
    unsigned short* __restrict__ WFlo)
{
    int idx = blockIdx.x * 256 + threadIdx.x;   // 32768
    int k = idx >> 7, n = idx & 127;
    float w = W[k * 128 + n];
    unsigned short hi = f2bf(w);
    unsigned short lo = f2bf(w - bf2f(hi));
    int nb = n >> 4, ln = n & 15, ks = k >> 5, lg = (k >> 3) & 3, e = k & 7;
    int off = (((nb * 8 + ks) * 4 + lg) * 16 + ln) * 8 + e;
    WFhi[off] = hi;
    WFlo[off] = lo;
}

// ---------------------------------------------------------------------------
// adj pack: byte (S,lg,w) = bits of adj[row][w*512+S*32+lg*8 ..+7]
// layout: mask bytes [row*256 + w*64 + lg*16 + S]
__global__ __launch_bounds__(256) void k_pack(
    const int* __restrict__ adj, unsigned int* __restrict__ mask)
{
    __shared__ unsigned char mb[256];
    int row = blockIdx.x;                       // 16384 = b*2048 + i
    int t = threadIdx.x;
    const int4* a4 = reinterpret_cast<const int4*>(adj + (size_t)row * N_) + 2 * t;
    int4 x = a4[0], y = a4[1];
    unsigned byte =
        (unsigned)(x.x > 0) | ((unsigned)(x.y > 0) << 1) |
        ((unsigned)(x.z > 0) << 2) | ((unsigned)(x.w > 0) << 3) |
        ((unsigned)(y.x > 0) << 4) | ((unsigned)(y.y > 0) << 5) |
        ((unsigned)(y.z > 0) << 6) | ((unsigned)(y.w > 0) << 7);
    int w = t >> 6, cig = t & 63;
    int S = cig >> 2, lg = cig & 3;
    mb[w * 64 + lg * 16 + S] = (unsigned char)byte;
    __syncthreads();
    if (t < 16)
        reinterpret_cast<uint4*>(mask)[row * 16 + t] =
            reinterpret_cast<const uint4*>(mb)[t];
}

// ---------------------------------------------------------------------------
// h = inp @ W via 3-term split-bf16 MFMA. 64 rows/block, 4 waves.
// W frags: coalesced 1KB loads (fragment-major). Output hF fragment-major:
// hF[b][J=j>>5][f][j&31], so k_attn B-frag loads are 1KB contiguous.
__global__ __launch_bounds__(256) void k_lin(
    const float* __restrict__ inp,
    const unsigned short* __restrict__ WFhi, const unsigned short* __restrict__ WFlo,
    const float* __restrict__ av, unsigned short* __restrict__ hF,
    float* __restrict__ s1, float* __restrict__ s2)
{
    __shared__ unsigned short Ahi[64 * 256];   // 32 KB, XOR-swizzled rows
    __shared__ unsigned short Alo[64 * 256];   // 32 KB

    int g = blockIdx.x;            // 256 blocks
    int b = g & 7;
    int i0 = (g >> 3) << 6;        // 64-row tile
    int t = threadIdx.x;

    {
        int row = t >> 2;
        const float* src = inp + ((size_t)(b * N_ + i0 + row)) * FIN + (t & 3) * 64;
#pragma unroll
        for (int gseg = 0; gseg < 8; ++gseg) {
            float4 f0 = *reinterpret_cast<const float4*>(src + gseg * 8);
            float4 f1 = *reinterpret_cast<const float4*>(src + gseg * 8 + 4);
            float f[8] = {f0.x, f0.y, f0.z, f0.w, f1.x, f1.y, f1.z, f1.w};
            bf16x8 hi8, lo8;
#pragma unroll
            for (int e = 0; e < 8; ++e) {
                unsigned short h = f2bf(f[e]);
                hi8[e] = (short)h;
                lo8[e] = (short)f2bf(f[e] - bf2f(h));
            }
            int k = (t & 3) * 64 + gseg * 8;
            int off = (row * 512 + k * 2) ^ ((row & 7) << 4);
            *reinterpret_cast<bf16x8*>(reinterpret_cast<char*>(Ahi) + off) = hi8;
            *reinterpret_cast<bf16x8*>(reinterpret_cast<char*>(Alo) + off) = lo8;
        }
    }
    __syncthreads();

    int w = t >> 6, l = t & 63;
    int ln = l & 15, lg = l >> 4;
    const bf16x8* Wh8 = reinterpret_cast<const bf16x8*>(WFhi);
    const bf16x8* Wl8 = reinterpret_cast<const bf16x8*>(WFlo);

    f32x4 acc[8];
#pragma unroll
    for (int nb = 0; nb < 8; ++nb) acc[nb] = (f32x4){0.f, 0.f, 0.f, 0.f};

#pragma unroll
    for (int ks = 0; ks < 8; ++ks) {
        int arow = w * 16 + ln;
        int aoff = (arow * 512 + ks * 64 + lg * 16) ^ ((arow & 7) << 4);
        bf16x8 ahi = *reinterpret_cast<const bf16x8*>(reinterpret_cast<const char*>(Ahi) + aoff);
        bf16x8 alo = *reinterpret_cast<const bf16x8*>(reinterpret_cast<const char*>(Alo) + aoff);
#pragma unroll
        for (int nb = 0; nb < 8; ++nb) {
            int fi = ((nb * 8 + ks) * 4 + lg) * 16 + ln;   // coalesced: lane-linear
            bf16x8 whi = Wh8[fi];
            bf16x8 wlo = Wl8[fi];
            acc[nb] = __builtin_amdgcn_mfma_f32_16x16x32_bf16(ahi, whi, acc[nb], 0, 0, 0);
            acc[nb] = __builtin_amdgcn_mfma_f32_16x16x32_bf16(alo, whi, acc[nb], 0, 0, 0);
            acc[nb] = __builtin_amdgcn_mfma_f32_16x16x32_bf16(ahi, wlo, acc[nb], 0, 0, 0);
        }
    }

    // s1/s2 (C/D layout: col=ln, row=lg*4+j)
    float p1[4] = {0.f, 0.f, 0.f, 0.f}, p2[4] = {0.f, 0.f, 0.f, 0.f};
#pragma unroll
    for (int nb = 0; nb < 8; ++nb) {
        float a1 = av[nb * 16 + ln];
        float a2 = av[FOUT + nb * 16 + ln];
#pragma unroll
        for (int j = 0; j < 4; ++j) {
            p1[j] = fmaf(acc[nb][j], a1, p1[j]);
            p2[j] = fmaf(acc[nb][j], a2, p2[j]);
        }
    }
#pragma unroll
    for (int off = 1; off < 16; off <<= 1)
#pragma unroll
        for (int j = 0; j < 4; ++j) {
            p1[j] += __shfl_xor(p1[j], off);
            p2[j] += __shfl_xor(p2[j], off);
        }
    if (ln == 0) {
#pragma unroll
        for (int j = 0; j < 4; ++j) {
            int row = i0 + w * 16 + lg * 4 + j;
            s1[b * N_ + row] = p1[j];
            s2[b * N_ + row] = p2[j];
        }
    }

    // transpose through LDS (reuse Ahi): T[128 f][68]
    __syncthreads();
    unsigned short* T = Ahi;
#pragma unroll
    for (int nb = 0; nb < 8; ++nb)
#pragma unroll
        for (int j = 0; j < 4; ++j)
            T[(nb * 16 + ln) * 68 + w * 16 + lg * 4 + j] = f2bf(acc[nb][j]);
    __syncthreads();
    {
        int f = t & 127, half = t >> 7;
        int J = (i0 >> 5) + half;
        unsigned short tmp[32];
#pragma unroll
        for (int c = 0; c < 32; ++c) tmp[c] = T[f * 68 + half * 32 + c];
        int4* dst = reinterpret_cast<int4*>(&hF[(((size_t)(b * 64 + J)) * 128 + f) * 32]);
#pragma unroll
        for (int c = 0; c < 4; ++c) dst[c] = reinterpret_cast<const int4*>(tmp)[c];
    }
}

// ---------------------------------------------------------------------------
__global__ __launch_bounds__(256) void k_s2max(const float* __restrict__ s2,
                                               float* __restrict__ s2max)
{
    __shared__ float red[4];
    int b = blockIdx.x, t = threadIdx.x;
    const float4* p = reinterpret_cast<const float4*>(s2 + b * N_);
    float4 v0 = p[t], v1 = p[t + 256];
    float m = fmaxf(fmaxf(fmaxf(v0.x, v0.y), fmaxf(v0.z, v0.w)),
                    fmaxf(fmaxf(v1.x, v1.y), fmaxf(v1.z, v1.w)));
#pragma unroll
    for (int off = 1; off < 64; off <<= 1) m = fmaxf(m, __shfl_xor(m, off));
    if ((t & 63) == 0) red[t >> 6] = m;
    __syncthreads();
    if (t == 0) s2max[b] = fmaxf(fmaxf(red[0], red[1]), fmaxf(red[2], red[3]));
}

// ---------------------------------------------------------------------------
// Fused attention: 32 rows/block (2 row-tiles share every B-fragment),
// fragment-major hF => every hv load is 1024B fully-coalesced, double-buffered.
__global__ __launch_bounds__(256) void k_attn(
    const unsigned int* __restrict__ mask, const unsigned short* __restrict__ hF,
    const float* __restrict__ s1g, const float* __restrict__ s2g,
    const float* __restrict__ s2maxg, float* __restrict__ out)
{
    __shared__ float s2_lds[N_];         // 8 KB
    __shared__ float accb[4][32][128];   // 64 KB (epilogue only)
    __shared__ float l_s[4][32];

    int g = blockIdx.x;                  // 512
    int b = g & 7;                       // XCD-affine
    int i0 = (g >> 3) << 5;              // 32 rows
    int t = threadIdx.x;
    int w = t >> 6, l = t & 63;
    int r = l & 15, lg = l >> 4;
    int jc = w * 512;

    {
        const float4* s2g4 = reinterpret_cast<const float4*>(s2g + b * N_);
        reinterpret_cast<float4*>(s2_lds)[t] = s2g4[t];
        reinterpret_cast<float4*>(s2_lds)[t + 256] = s2g4[t + 256];
    }

    const float s2m = s2maxg[b];
    const float s1r0 = s1g[b * N_ + i0 + r];
    const float s1r1 = s1g[b * N_ + i0 + 16 + r];
    float eb0 = s1r0 + s2m, eb1 = s1r1 + s2m;
    const float m0 = fmaxf(eb0, ALPHA * eb0);
    const float m1 = fmaxf(eb1, ALPHA * eb1);

    uint4 m40 = *reinterpret_cast<const uint4*>(
        reinterpret_cast<const char*>(mask) +
        ((size_t)(b * N_ + i0 + r)) * 256 + w * 64 + lg * 16);
    uint4 m41 = *reinterpret_cast<const uint4*>(
        reinterpret_cast<const char*>(mask) +
        ((size_t)(b * N_ + i0 + 16 + r)) * 256 + w * 64 + lg * 16);
    unsigned mw0[4] = {m40.x, m40.y, m40.z, m40.w};
    unsigned mw1[4] = {m41.x, m41.y, m41.z, m41.w};

    // hv frag (S,q): hF[((b*64 + w*16 + S)*128 + q*16 + r)*32 + lg*8 ..]
    const bf16x8* hv = reinterpret_cast<const bf16x8*>(hF)
        + (((size_t)(b * 64 + w * 16) * 128 + r) * 4 + lg);
    // step stride 512 (bf16x8), frag stride 64

    __syncthreads();   // s2_lds ready

    float l0 = 0.f, l1 = 0.f;
    f32x4 acc0[8], acc1[8];
#pragma unroll
    for (int q = 0; q < 8; ++q) {
        acc0[q] = (f32x4){0.f, 0.f, 0.f, 0.f};
        acc1[q] = (f32x4){0.f, 0.f, 0.f, 0.f};
    }

    bf16x8 hA[8], hB[8];
#pragma unroll
    for (int q = 0; q < 8; ++q) hA[q] = hv[q * 64];

#pragma unroll
    for (int S = 0; S < 16; ++S) {
        auto& cur = (S & 1) ? hB : hA;
        auto& nxt = (S & 1) ? hA : hB;
        if (S < 15) {
#pragma unroll
            for (int q = 0; q < 8; ++q) nxt[q] = hv[(S + 1) * 512 + q * 64];
        }
        unsigned byte0 = (mw0[S >> 2] >> ((S & 3) * 8)) & 0xffu;
        unsigned byte1 = (mw1[S >> 2] >> ((S & 3) * 8)) & 0xffu;
        const float* s2b = &s2_lds[jc + S * 32 + lg * 8];
        float4 ca = *reinterpret_cast<const float4*>(s2b);
        float4 cb = *reinterpret_cast<const float4*>(s2b + 4);
        float sv[8] = {ca.x, ca.y, ca.z, ca.w, cb.x, cb.y, cb.z, cb.w};

        bf16x8 af0, af1;
        float ps0 = 0.f, ps1 = 0.f;
#pragma unroll
        for (int e = 0; e < 8; ++e) {
            float v0 = s1r0 + sv[e];
            v0 = fmaxf(v0, ALPHA * v0);
            float p0 = (byte0 & (1u << e)) ? __expf(v0 - m0) : 0.f;
            ps0 += p0;
            af0[e] = (short)f2bf(p0);
            float v1 = s1r1 + sv[e];
            v1 = fmaxf(v1, ALPHA * v1);
            float p1 = (byte1 & (1u << e)) ? __expf(v1 - m1) : 0.f;
            ps1 += p1;
            af1[e] = (short)f2bf(p1);
        }
        l0 += ps0;
        l1 += ps1;
#pragma unroll
        for (int q = 0; q < 8; ++q) {
            acc0[q] = __builtin_amdgcn_mfma_f32_16x16x32_bf16(af0, cur[q], acc0[q], 0, 0, 0);
            acc1[q] = __builtin_amdgcn_mfma_f32_16x16x32_bf16(af1, cur[q], acc1[q], 0, 0, 0);
        }
    }

    l0 += __shfl_xor(l0, 16);
    l0 += __shfl_xor(l0, 32);
    l1 += __shfl_xor(l1, 16);
    l1 += __shfl_xor(l1, 32);
    if (l < 16) {
        l_s[w][l] = l0;
        l_s[w][16 + l] = l1;
    }

#pragma unroll
    for (int q = 0; q < 8; ++q)
#pragma unroll
        for (int rr = 0; rr < 4; ++rr) {
            accb[w][lg * 4 + rr][q * 16 + r] = acc0[q][rr];
            accb[w][16 + lg * 4 + rr][q * 16 + r] = acc1[q][rr];
        }
    __syncthreads();

    int f = t & 127, rh = t >> 7;
#pragma unroll
    for (int rr = 0; rr < 16; ++rr) {
        int row = rh * 16 + rr;
        float L = l_s[0][row] + l_s[1][row] + l_s[2][row] + l_s[3][row];
        float v = accb[0][row][f] + accb[1][row][f] + accb[2][row][f] + accb[3][row][f];
        out[((size_t)(b * N_ + i0 + row)) * FOUT + f] = fmaxf(v / L, 0.f);
    }
}

extern "C" void kernel_launch(void* const* d_in, const int* in_sizes, int n_in,
                              void* d_out, int out_size, void* d_ws, size_t ws_size,
                              hipStream_t stream) {
    (void)in_sizes; (void)n_in; (void)out_size; (void)ws_size;
    const float* inp = (const float*)d_in[0];
    const int*   adj = (const int*)d_in[1];
    const float* W   = (const float*)d_in[2];
    const float* a   = (const float*)d_in[3];
    float* out = (float*)d_out;

    char* ws = (char*)d_ws;
    unsigned short* hF   = (unsigned short*)ws;                         // 4 MB
    unsigned int*   mask = (unsigned int*)(ws + (4u << 20));            // 4 MB
    float* s1    = (float*)(ws + (8u << 20));                           // 64 KB
    float* s2    = s1 + 8 * N_;                                         // 64 KB
    unsigned short* WFhi = (unsigned short*)(s2 + 8 * N_);              // 64 KB
    unsigned short* WFlo = WFhi + FIN * FOUT;                           // 64 KB
    float* s2max = (float*)(WFlo + FIN * FOUT);                         // 32 B

    k_wsplit<<<128, 256, 0, stream>>>(W, WFhi, WFlo);
    k_pack<<<8 * N_, 256, 0, stream>>>(adj, mask);
    k_lin<<<256, 256, 0, stream>>>(inp, WFhi, WFlo, a, hF, s1, s2);
    k_s2max<<<8, 256, 0, stream>>>(s2, s2max);
    k_attn<<<512, 256, 0, stream>>>(mask, hF, s1, s2, s2max, out);
}